// Round 1
// 808.279 us; speedup vs baseline: 1.1474x; 1.1474x over previous
//
#include <hip/hip_runtime.h>

#define L_LEN 512
#define D_DIM 4096
#define H_NUM 8
#define B_NUM 16
#define TOPK  12

// ---------------------------------------------------------------------------
// Stage A: per-channel circular cross-correlation + top-12 + softmax.
// grid = B*H*64 blocks of 256 threads (4 waves, 8 channels, 2 ch/wave).
// Lane l: ch = wave*2 + (l>>5), owns taus tau0..tau0+15, tau0 = (l&31)*16.
// LDS q layout: padded word PW(t) = t + 4*(t>>4)  (pad 4 words per 16):
//   - lane word-stride 20 -> bank-group stride 5 -> <=2-way conflicts (free)
//   - linear in t: PW(t+16)=PW(t)+20, PW(t+512)=PW(t)+640 -> ds offsets fold
// ---------------------------------------------------------------------------

#define LOADQK(QV, KV, QWOFF, TOFF) do {                                      \
    _Pragma("unroll")                                                         \
    for (int x = 0; x < 4; ++x) {                                             \
      const float4 v = *(const float4*)(qc + (QWOFF) + 4 * x);                \
      QV[4*x+0] = v.x; QV[4*x+1] = v.y; QV[4*x+2] = v.z; QV[4*x+3] = v.w;     \
    }                                                                         \
    _Pragma("unroll")                                                         \
    for (int x = 0; x < 4; ++x) {                                             \
      const float4 v = *(const float4*)(qc + (QWOFF) + 20 + 4 * x);           \
      QV[16+4*x+0] = v.x; QV[16+4*x+1] = v.y;                                 \
      QV[16+4*x+2] = v.z; QV[16+4*x+3] = v.w;                                 \
    }                                                                         \
    _Pragma("unroll")                                                         \
    for (int x = 0; x < 4; ++x) {                                             \
      const float4 v = *(const float4*)(kc + (TOFF) + 4 * x);                 \
      KV[4*x+0] = v.x; KV[4*x+1] = v.y; KV[4*x+2] = v.z; KV[4*x+3] = v.w;     \
    }                                                                         \
  } while (0)

#define MACBLK(QV, KV) do {                                                   \
    _Pragma("unroll")                                                         \
    for (int tt = 0; tt < 16; ++tt)                                           \
      _Pragma("unroll")                                                       \
      for (int ii = 0; ii < 16; ++ii)                                         \
        acc[ii] = fmaf(QV[ii + tt], KV[tt], acc[ii]);                         \
  } while (0)

__global__ __launch_bounds__(256, 2) void corr_topk_kernel(
    const float* __restrict__ Q, const float* __restrict__ K,
    float* __restrict__ ws_w, int* __restrict__ ws_i)
{
  __shared__ float qs[8][1312];   // 41984 B (padded rows; real data <=1275)
  __shared__ float ks[8][544];    // 17408 B (512 + slack for tail prefetch)

  const int tid = threadIdx.x;
  const int bid = blockIdx.x;
  // chunked XCD remap: all 64 blocks of one bh land on one XCD (L2 merge of
  // the 32B row slices). 8192 = 8 xcd * 1024.
  const int work = (bid & 7) * 1024 + (bid >> 3);
  const int bh   = work >> 6;
  const int cblk = work & 63;
  const int c0   = cblk * 8;

  const size_t base = (size_t)(bh >> 3) * (size_t)(L_LEN * D_DIM)
                    + (size_t)(bh & 7) * 512 + c0;

  // staging: thread loads float4 = 4 channels of one row t (coalesced 32B
  // per row; co-XCD blocks merge to full lines in L2).
  #pragma unroll
  for (int rep = 0; rep < 4; ++rep) {
    const int idx  = rep * 256 + tid;       // 0..1023
    const int t    = idx >> 1;
    const int half = idx & 1;
    const float4 qv = *(const float4*)(Q + base + (size_t)t * D_DIM + half * 4);
    const float4 kv = *(const float4*)(K + base + (size_t)t * D_DIM + half * 4);
    const int w  = t + ((t >> 4) << 2);     // PW(t)
    const int cb = half * 4;
    const float qa[4] = {qv.x, qv.y, qv.z, qv.w};
    const float ka[4] = {kv.x, kv.y, kv.z, kv.w};
    #pragma unroll
    for (int j = 0; j < 4; ++j) {
      qs[cb + j][w]       = qa[j];
      qs[cb + j][w + 640] = qa[j];          // PW(t+512) == PW(t)+640
      ks[cb + j][t]       = ka[j];
    }
  }
  __syncthreads();

  const int wave = tid >> 6;
  const int lane = tid & 63;
  const int ch   = wave * 2 + (lane >> 5);
  const int m    = lane & 31;               // tau0 = 16*m

  const float* __restrict__ qc = qs[ch];
  const float* __restrict__ kc = ks[ch];

  float acc[16];
  #pragma unroll
  for (int i = 0; i < 16; ++i) acc[i] = 0.f;

  // qw = PW(16m + t0); starts at 20m, advances by 20 per 16-t block.
  int qw = 20 * m;
  float qvA[32], kvA[16], qvB[32], kvB[16];
  LOADQK(qvA, kvA, qw, 0);
  #pragma unroll 1
  for (int t0 = 0; t0 < 512; t0 += 32) {
    LOADQK(qvB, kvB, qw + 20, t0 + 16);     // prefetch next block
    MACBLK(qvA, kvA);
    LOADQK(qvA, kvA, qw + 40, t0 + 32);     // prefetch next-next (tail: junk, unused)
    MACBLK(qvB, kvB);
    qw += 40;
  }

  // ---- top-12 via repeated argmax over the 32-lane channel group
  const int tau0 = m * 16;
  float bv[TOPK]; int bi[TOPK];
  #pragma unroll
  for (int s = 0; s < TOPK; ++s) {
    float lv = acc[0]; int li = 0;
    #pragma unroll
    for (int i = 1; i < 16; ++i) if (acc[i] > lv) { lv = acc[i]; li = i; }
    int gi = tau0 + li;
    #pragma unroll
    for (int off = 16; off >= 1; off >>= 1) {
      const float ov = __shfl_xor(lv, off, 32);
      const int   oi = __shfl_xor(gi, off, 32);
      if (ov > lv || (ov == lv && oi < gi)) { lv = ov; gi = oi; }
    }
    bv[s] = lv; bi[s] = gi;
    const int slot = gi - tau0;
    #pragma unroll
    for (int i = 0; i < 16; ++i) acc[i] = (slot == i) ? -3.4e38f : acc[i];
  }

  float e[TOPK]; float sum = 0.f;
  #pragma unroll
  for (int s = 0; s < TOPK; ++s) { e[s] = expf(bv[s] - bv[0]); sum += e[s]; }
  const float inv = 1.f / sum;

  if (m == 0) {
    const int g = (bh * 512 + c0 + ch) * TOPK;
    #pragma unroll
    for (int s = 0; s < TOPK; ++s) { ws_w[g + s] = e[s] * inv; ws_i[g + s] = bi[s]; }
  }
}

// ---------------------------------------------------------------------------
// Stage B: block = (b, 32-column window of D). 512 threads (8 waves),
// vs[512][32] staged in descending quarters. Since r = min(r0+t,511) >= t,
// outputs t in [ph*128,(ph+1)*128) only read rows >= ph*128: later stagings
// write strictly lower rows than any concurrent reader -> 1 barrier/phase.
// Next quarter's loads are issued to regs BEFORE the barrier; raw
// s_barrier (lgkmcnt only) keeps them in flight across it.
// grid = 16*128 = 2048 blocks.
// ---------------------------------------------------------------------------
__global__ __launch_bounds__(512, 4) void gather_kernel(
    const float* __restrict__ V, const float* __restrict__ ws_w,
    const int* __restrict__ ws_i, float* __restrict__ out)
{
  __shared__ float vs[512][32];   // 65536 B

  const int tid = threadIdx.x;
  const int bid = blockIdx.x;
  // chunked XCD remap: 2048 = 8 xcd * 256 (each XCD: 2 b's, contiguous dg)
  const int work = (bid & 7) * 256 + (bid >> 3);
  const int b  = work >> 7;
  const int dg = work & 127;
  const int d0 = dg * 32;
  const int h  = d0 >> 9;
  const int c0 = d0 & 511;

  const size_t vcol = (size_t)b * (size_t)(L_LEN * D_DIM) + d0;

  const int cl   = tid & 31;
  const int tsub = tid >> 5;              // 0..15

  float4 stga, stgb;
  const int e0 = tid, e1 = 512 + tid;
  const int ra0 = e0 >> 3, qa0 = (e0 & 7) * 4;
  const int rb0 = e1 >> 3, qb0 = (e1 & 7) * 4;

  // prologue: issue loads for phase 3
  stga = *(const float4*)(V + vcol + (size_t)(3 * 128 + ra0) * D_DIM + qa0);
  stgb = *(const float4*)(V + vcol + (size_t)(3 * 128 + rb0) * D_DIM + qb0);

  // per-thread top-k data (16x duplicated across tsub; small, L2-resident)
  const int g = ((b * 8 + h) * 512 + c0 + cl) * TOPK;
  float w[TOPK]; int r0[TOPK];
  #pragma unroll
  for (int s = 0; s < TOPK; ++s) { w[s] = ws_w[g + s]; r0[s] = ws_i[g + s]; }

  const size_t ob = vcol + cl;

  #pragma unroll 1
  for (int ph = 3; ph >= 0; --ph) {
    // commit staged quarter (compiler inserts vmcnt wait for stga/stgb)
    *(float4*)(&vs[ph * 128 + ra0][qa0]) = stga;
    *(float4*)(&vs[ph * 128 + rb0][qb0]) = stgb;
    if (ph > 0) {  // issue next quarter early; stays in flight across barrier
      stga = *(const float4*)(V + vcol + (size_t)((ph - 1) * 128 + ra0) * D_DIM + qa0);
      stgb = *(const float4*)(V + vcol + (size_t)((ph - 1) * 128 + rb0) * D_DIM + qb0);
    }
    asm volatile("s_waitcnt lgkmcnt(0)" ::: "memory");
    __builtin_amdgcn_s_barrier();
    asm volatile("" ::: "memory");

    // compute outputs t in [ph*128, (ph+1)*128)
    #pragma unroll
    for (int k8 = 0; k8 < 8; ++k8) {
      const int t = ph * 128 + (k8 << 4) + tsub;
      float a = 0.f;
      #pragma unroll
      for (int s = 0; s < TOPK; ++s) {
        int r = r0[s] + t;
        r = r > (L_LEN - 1) ? (L_LEN - 1) : r;
        a = fmaf(w[s], vs[r][cl], a);       // bank = cl: scatter-immune
      }
      out[ob + (size_t)t * D_DIM] = a;
    }
  }
}

extern "C" void kernel_launch(void* const* d_in, const int* in_sizes, int n_in,
                              void* d_out, int out_size, void* d_ws, size_t ws_size,
                              hipStream_t stream)
{
  const float* Q = (const float*)d_in[0];
  const float* K = (const float*)d_in[1];
  const float* V = (const float*)d_in[2];
  float* out = (float*)d_out;

  float* ws_w = (float*)d_ws;
  int*   ws_i = (int*)((char*)d_ws + (size_t)B_NUM * H_NUM * 512 * TOPK * sizeof(float));

  corr_topk_kernel<<<dim3(B_NUM * H_NUM * 64), dim3(256), 0, stream>>>(Q, K, ws_w, ws_i);
  gather_kernel<<<dim3(B_NUM * H_NUM * 16), dim3(512), 0, stream>>>(V, ws_w, ws_i, out);
}